// Round 3
// baseline (712.133 us; speedup 1.0000x reference)
//
#include <hip/hip_runtime.h>
#include <hip/hip_bf16.h>
#include <math.h>

typedef __bf16 bhalf;
typedef __bf16 bhalf8 __attribute__((ext_vector_type(8)));
typedef float  floatx4 __attribute__((ext_vector_type(4)));
typedef float  floatx8 __attribute__((ext_vector_type(8)));
typedef unsigned short ushort_t;
typedef unsigned short ushort8 __attribute__((ext_vector_type(8)));

#define MFMA16(a, b, c) __builtin_amdgcn_mfma_f32_16x16x32_bf16((a), (b), (c), 0, 0, 0)

enum { EPI_PLAIN = 0, EPI_RES = 1, EPI_GELU = 2, EPI_VT = 3 };

// ---------------------------------------------------------------------------
// Dtype detector: if d_in really holds fp32 (per the jnp.float32 reference),
// the even-indexed 16-bit words are fp32 low-mantissa bits -> reinterpreted
// as bf16 they have uniform random exponents (~44% >= 0x90). True bf16
// N(0,1) data never exceeds exponent 0x81. Writes flag: 1 = fp32, 0 = bf16.
// ---------------------------------------------------------------------------
__global__ __launch_bounds__(256) void detect_dtype(const ushort_t* __restrict__ x,
                                                    int* __restrict__ flag)
{
    __shared__ int tot;
    if (threadIdx.x == 0) tot = 0;
    __syncthreads();
    int cnt = 0;
    for (int i = threadIdx.x; i < 8192; i += 256) {
        const ushort_t u = x[2 * i];          // even-indexed 16-bit word
        const int e = (u >> 7) & 0xFF;        // bf16 exponent field
        if (e >= 0x90) ++cnt;                 // |v| >= 2^17: impossible for real data
    }
    atomicAdd(&tot, cnt);
    __syncthreads();
    if (threadIdx.x == 0) flag[0] = (tot > 64) ? 1 : 0;
}

// ---------------------------------------------------------------------------
// Normalize all inputs to bf16 ws copies (fp32 -> cvt, bf16 -> copy).
// grid.y = tensor index, grid.x covers elements (8/thread); extra blocks exit.
// ---------------------------------------------------------------------------
struct Cvt { const void* s; bhalf* d; int n; };
struct CvtArr { Cvt t[17]; };

__global__ __launch_bounds__(256) void normalize_all(CvtArr a, const int* __restrict__ flag)
{
    const Cvt c = a.t[blockIdx.y];
    const int i = (blockIdx.x * 256 + threadIdx.x) * 8;
    if (i >= c.n) return;
    if (*flag) {
        const floatx8 v = *(const floatx8*)((const float*)c.s + i);
        bhalf8 o;
#pragma unroll
        for (int j = 0; j < 8; ++j) o[j] = (bhalf)v[j];
        *(bhalf8*)(c.d + i) = o;
    } else {
        *(ushort8*)((ushort_t*)c.d + i) = *(const ushort8*)((const ushort_t*)c.s + i);
    }
}

// ---------------------------------------------------------------------------
// GEMM: C[M,N] = A[M,K] @ B[K,N] + bias, B in NATURAL [K][N] layout (bf16).
// 64x64 tile, BK=64, 256 threads = 4 waves (2x2), wave does 32x32 via 2x2
// MFMA 16x16x32 bf16 tiles, fp32 accum. B staged transposed into LDS with an
// XOR-chunk swizzle: B[k][n] -> Bs[n*72 + (((k>>3)^((n>>3)&7))<<3) + (k&7)].
// ---------------------------------------------------------------------------
template <int EPI>
__global__ __launch_bounds__(256) void gemm_bn(
    const bhalf* __restrict__ A, int lda,
    const bhalf* __restrict__ B, int ldb,
    const bhalf* __restrict__ bias,
    const bhalf* __restrict__ resid,
    bhalf* __restrict__ C, int ldc, int K)
{
    __shared__ __align__(16) bhalf As[64 * 72];  // As[m][k], +8 pad
    __shared__ __align__(16) bhalf Bs[64 * 72];  // swizzled Bs[n][k]

    const int tid  = threadIdx.x;
    const int lane = tid & 63;
    const int w    = tid >> 6;
    const int l15  = lane & 15;
    const int q    = lane >> 4;
    const int wm   = (w >> 1) * 32;
    const int wn   = (w & 1) * 32;
    const int n0   = blockIdx.x * 64;
    const int m0   = blockIdx.y * 64;

    const int tr = tid >> 3;        // 0..31
    const int tc = (tid & 7) * 8;   // 0..56 step 8
    const int u  = tid & 7;         // = (tc+j)>>3 for j in 0..7

    floatx4 acc[2][2];
#pragma unroll
    for (int i = 0; i < 2; ++i)
#pragma unroll
        for (int j = 0; j < 2; ++j) acc[i][j] = (floatx4){0.f, 0.f, 0.f, 0.f};

    const int c0 = tr >> 3;        // k-chunk of row tr      (0..3)
    const int c1 = (tr + 32) >> 3; // k-chunk of row tr+32   (4..7)

    for (int k0 = 0; k0 < K; k0 += 64) {
        const bhalf* ga = A + (size_t)(m0 + tr) * lda + k0 + tc;
        const bhalf* gb = B + (size_t)(k0 + tr) * ldb + n0 + tc;
        bhalf8 a0 = *(const bhalf8*)ga;
        bhalf8 a1 = *(const bhalf8*)(ga + (size_t)32 * lda);
        bhalf8 b0 = *(const bhalf8*)gb;
        bhalf8 b1 = *(const bhalf8*)(gb + (size_t)32 * ldb);
        __syncthreads();  // previous iteration's LDS reads complete
        *(bhalf8*)&As[tr * 72 + tc]        = a0;
        *(bhalf8*)&As[(tr + 32) * 72 + tc] = a1;
#pragma unroll
        for (int j = 0; j < 8; ++j) {
            Bs[(tc + j) * 72 + ((c0 ^ u) << 3) + (tr & 7)] = b0[j];
            Bs[(tc + j) * 72 + ((c1 ^ u) << 3) + (tr & 7)] = b1[j];
        }
        __syncthreads();
#pragma unroll
        for (int s = 0; s < 2; ++s) {
            bhalf8 af0 = *(const bhalf8*)&As[(wm + l15) * 72 + s * 32 + q * 8];
            bhalf8 af1 = *(const bhalf8*)&As[(wm + 16 + l15) * 72 + s * 32 + q * 8];
            const int nb0 = wn + l15;
            const int nb1 = wn + 16 + l15;
            bhalf8 bf0 = *(const bhalf8*)&Bs[nb0 * 72 + (((s * 4 + q) ^ ((nb0 >> 3) & 7)) << 3)];
            bhalf8 bf1 = *(const bhalf8*)&Bs[nb1 * 72 + (((s * 4 + q) ^ ((nb1 >> 3) & 7)) << 3)];
            acc[0][0] = MFMA16(af0, bf0, acc[0][0]);
            acc[0][1] = MFMA16(af0, bf1, acc[0][1]);
            acc[1][0] = MFMA16(af1, bf0, acc[1][0]);
            acc[1][1] = MFMA16(af1, bf1, acc[1][1]);
        }
    }

#pragma unroll
    for (int mt = 0; mt < 2; ++mt)
#pragma unroll
        for (int nt = 0; nt < 2; ++nt) {
            const int col = n0 + wn + nt * 16 + l15;
            const float bv = (float)bias[col];
#pragma unroll
            for (int r = 0; r < 4; ++r) {
                const int row = m0 + wm + mt * 16 + q * 4 + r;  // C/D: row=q*4+r, col=l15 (m89)
                float v = acc[mt][nt][r] + bv;
                if constexpr (EPI == EPI_PLAIN) {
                    C[(size_t)row * ldc + col] = (bhalf)v;
                } else if constexpr (EPI == EPI_RES) {
                    v += (float)resid[(size_t)row * ldc + col];
                    C[(size_t)row * ldc + col] = (bhalf)v;
                } else if constexpr (EPI == EPI_GELU) {
                    v = 0.5f * v * (1.f + erff(v * 0.70710678118654752f));
                    C[(size_t)row * ldc + col] = (bhalf)v;
                } else {  // EPI_VT: scatter V transposed per head: Vt[b][h][kk][t]
                    const int b = row >> 11, l = row & 2047;
                    const int h = col >> 6, kk = col & 63;
                    C[(((size_t)(b * 16 + h) * 64 + kk) << 11) + l] = (bhalf)v;
                }
            }
        }
}

// ---------------------------------------------------------------------------
// Attention: one block = one (b,h) pair x 16 queries. Scores 16x2048 bf16 in
// 64KB LDS, XOR-chunk swizzle (physical chunk = (n>>3) ^ (m&7)).
// ---------------------------------------------------------------------------
__global__ __launch_bounds__(256) void attn_kernel(
    const bhalf* __restrict__ Q, const bhalf* __restrict__ Km,
    const bhalf* __restrict__ Vt, bhalf* __restrict__ ctx)
{
    __shared__ __align__(16) bhalf sc[16 * 2048];  // exactly 64 KB

    const int tid  = threadIdx.x;
    const int lane = tid & 63;
    const int w    = tid >> 6;
    const int l15  = lane & 15;
    const int q    = lane >> 4;
    const int bh   = blockIdx.y;
    const int b    = bh >> 4, h = bh & 15;
    const int l0   = blockIdx.x * 16;

    // ---- phase 1: S = Q K^T / 8 ----
    const bhalf* qp = Q + ((size_t)(b * 2048 + l0 + l15)) * 1024 + h * 64 + q * 8;
    const bhalf8 aQ0 = *(const bhalf8*)qp;
    const bhalf8 aQ1 = *(const bhalf8*)(qp + 32);
    const bhalf* kb = Km + ((size_t)b * 2048) * 1024 + h * 64 + q * 8;
    for (int nt = w * 32; nt < w * 32 + 32; ++nt) {
        const bhalf* kp = kb + (size_t)(nt * 16 + l15) * 1024;
        bhalf8 bK0 = *(const bhalf8*)kp;
        bhalf8 bK1 = *(const bhalf8*)(kp + 32);
        floatx4 a = (floatx4){0.f, 0.f, 0.f, 0.f};
        a = MFMA16(aQ0, bK0, a);
        a = MFMA16(aQ1, bK1, a);
#pragma unroll
        for (int r = 0; r < 4; ++r) {
            const int m = q * 4 + r;
            const int n = nt * 16 + l15;
            const int cs = (n >> 3) ^ (m & 7);
            sc[m * 2048 + cs * 8 + (n & 7)] = (bhalf)(a[r] * 0.125f);
        }
    }
    __syncthreads();

    // ---- phase 2: softmax per row; 16 lanes/row, each lane owns its chunks ----
    {
        const int row = tid >> 4;
        const int sub = tid & 15;
        bhalf* rp = sc + row * 2048;
        const int sw = row & 7;
        float mx = -3.0e38f;
        for (int c = sub * 16; c < sub * 16 + 16; ++c) {
            bhalf8 vv = *(const bhalf8*)(rp + ((c ^ sw) << 3));
#pragma unroll
            for (int j = 0; j < 8; ++j) mx = fmaxf(mx, (float)vv[j]);
        }
#pragma unroll
        for (int off = 8; off >= 1; off >>= 1) mx = fmaxf(mx, __shfl_xor(mx, off, 16));
        float sum = 0.f;
        for (int c = sub * 16; c < sub * 16 + 16; ++c) {
            bhalf8 vv = *(const bhalf8*)(rp + ((c ^ sw) << 3));
            bhalf8 ev;
#pragma unroll
            for (int j = 0; j < 8; ++j) {
                const float e = expf((float)vv[j] - mx);
                sum += e;
                ev[j] = (bhalf)e;
            }
            *(bhalf8*)(rp + ((c ^ sw) << 3)) = ev;
        }
#pragma unroll
        for (int off = 8; off >= 1; off >>= 1) sum += __shfl_xor(sum, off, 16);
        const float inv = 1.f / sum;
        for (int c = sub * 16; c < sub * 16 + 16; ++c) {
            bhalf8 vv = *(const bhalf8*)(rp + ((c ^ sw) << 3));
#pragma unroll
            for (int j = 0; j < 8; ++j) vv[j] = (bhalf)((float)vv[j] * inv);
            *(bhalf8*)(rp + ((c ^ sw) << 3)) = vv;
        }
    }
    __syncthreads();

    // ---- phase 3: O = P V  (wave w covers head-dims w*16..w*16+15) ----
    {
        floatx4 a = (floatx4){0.f, 0.f, 0.f, 0.f};
        const bhalf* vb = Vt + ((size_t)bh * 64 + w * 16 + l15) * 2048 + q * 8;
        const bhalf* pr = sc + l15 * 2048;  // A-frag row m = lane&15
        const int sw = l15 & 7;
        for (int s = 0; s < 64; ++s) {
            bhalf8 aP = *(const bhalf8*)(pr + (((s * 4 + q) ^ sw) << 3));
            bhalf8 bV = *(const bhalf8*)(vb + s * 32);
            a = MFMA16(aP, bV, a);
        }
        // faithful reshape (b,h,L,dk)->(b,L,d) without transpose:
#pragma unroll
        for (int r = 0; r < 4; ++r) {
            const int m = q * 4 + r;
            const int l = l0 + m;
            const int kk = w * 16 + l15;
            const int R = h * 128 + (l >> 4);
            const int Cc = (l & 15) * 64 + kk;
            ctx[((size_t)(b * 2048 + R)) * 1024 + Cc] = (bhalf)a[r];
        }
    }
}

// ---------------------------------------------------------------------------
// Row LayerNorm over 1024 cols, one block per row, fp32 stats.
// If flag != nullptr and *flag: store fp32 to out; else store bf16.
// ---------------------------------------------------------------------------
__global__ __launch_bounds__(256) void ln_kernel(
    const bhalf* __restrict__ X, const bhalf* __restrict__ g,
    const bhalf* __restrict__ be, void* __restrict__ out, const int* __restrict__ flag)
{
    __shared__ float red[8];
    __shared__ float stats[2];
    const int row = blockIdx.x;
    const int tid = threadIdx.x;
    const bhalf* xr = X + (size_t)row * 1024;
    float v[4], s1 = 0.f, s2 = 0.f;
#pragma unroll
    for (int i = 0; i < 4; ++i) {
        v[i] = (float)xr[tid * 4 + i];
        s1 += v[i];
        s2 += v[i] * v[i];
    }
#pragma unroll
    for (int off = 32; off >= 1; off >>= 1) {
        s1 += __shfl_down(s1, off, 64);
        s2 += __shfl_down(s2, off, 64);
    }
    if ((tid & 63) == 0) { red[tid >> 6] = s1; red[4 + (tid >> 6)] = s2; }
    __syncthreads();
    if (tid == 0) {
        const float t1 = red[0] + red[1] + red[2] + red[3];
        const float t2 = red[4] + red[5] + red[6] + red[7];
        const float mu = t1 * (1.f / 1024.f);
        const float var = t2 * (1.f / 1024.f) - mu * mu;
        stats[0] = mu;
        stats[1] = rsqrtf(var + 1e-5f);
    }
    __syncthreads();
    const float mu = stats[0], rs = stats[1];
    const bool f32 = flag && (*flag != 0);
#pragma unroll
    for (int i = 0; i < 4; ++i) {
        const int j = tid * 4 + i;
        const float o = ((v[i] - mu) * rs) * (float)g[j] + (float)be[j];
        if (f32) ((float*)out)[(size_t)row * 1024 + j] = o;
        else     ((bhalf*)out)[(size_t)row * 1024 + j] = (bhalf)o;
    }
}

// ---------------------------------------------------------------------------
extern "C" void kernel_launch(void* const* d_in, const int* in_sizes, int n_in,
                              void* d_out, int out_size, void* d_ws, size_t ws_size,
                              hipStream_t stream)
{
    (void)in_sizes; (void)n_in; (void)out_size; (void)ws_size;

    char* p = (char*)d_ws;
    const size_t MB = 1024 * 1024;
    // Workspace (peak 65 MB), liveness-verified aliasing:
    //  0MB:      flag (int at byte 0), vec slots at 128KB (10 x 8KB bf16 slots)
    //  1-9:      Qw   -> ln1 (after attn) -> ff2 (after ln1 consumed)
    //  9-17:     Kw   -> x1
    //  17-25:    Vt   \
    //  25-33:    ctx   > ff1 = 17-49 (Vt/ctx/x_n/Wqkvo all dead by ff1-gemm)
    //  33-41:    x_n  /
    //  41-49:    Wq_n,Wk_n,Wv_n,Wo_n (2MB each)
    //  49-57:    W1_n
    //  57-65:    W2_n
    int*   flag = (int*)p;
    bhalf* vecs = (bhalf*)(p + 128 * 1024);
    bhalf* Qw   = (bhalf*)(p + 1 * MB);
    bhalf* Kw   = (bhalf*)(p + 9 * MB);
    bhalf* Vt   = (bhalf*)(p + 17 * MB);
    bhalf* ctx  = (bhalf*)(p + 25 * MB);
    bhalf* x_n  = (bhalf*)(p + 33 * MB);
    bhalf* Wq_n = (bhalf*)(p + 41 * MB);
    bhalf* Wk_n = (bhalf*)(p + 43 * MB);
    bhalf* Wv_n = (bhalf*)(p + 45 * MB);
    bhalf* Wo_n = (bhalf*)(p + 47 * MB);
    bhalf* W1_n = (bhalf*)(p + 49 * MB);
    bhalf* W2_n = (bhalf*)(p + 57 * MB);
    bhalf* ff1  = (bhalf*)(p + 17 * MB);  // 32 MB
    bhalf* ln1  = Qw;
    bhalf* x1   = Kw;
    bhalf* ff2  = Qw;

    bhalf* bq_n = vecs + 0 * 4096, *bk_n = vecs + 1 * 4096, *bv_n = vecs + 2 * 4096;
    bhalf* bo_n = vecs + 3 * 4096, *b1_n = vecs + 4 * 4096, *b2_n = vecs + 5 * 4096;
    bhalf* g1_n = vecs + 6 * 4096, *be1_n = vecs + 7 * 4096;
    bhalf* g2_n = vecs + 8 * 4096, *be2_n = vecs + 9 * 4096;

    const dim3 blk(256);

    detect_dtype<<<1, blk, 0, stream>>>((const ushort_t*)d_in[0], flag);

    CvtArr arr;
    arr.t[0]  = {d_in[0],  x_n,  2 * 2048 * 1024};
    arr.t[1]  = {d_in[1],  Wq_n, 1024 * 1024};
    arr.t[2]  = {d_in[3],  Wk_n, 1024 * 1024};
    arr.t[3]  = {d_in[5],  Wv_n, 1024 * 1024};
    arr.t[4]  = {d_in[7],  Wo_n, 1024 * 1024};
    arr.t[5]  = {d_in[9],  W1_n, 1024 * 4096};
    arr.t[6]  = {d_in[11], W2_n, 4096 * 1024};
    arr.t[7]  = {d_in[2],  bq_n, 1024};
    arr.t[8]  = {d_in[4],  bk_n, 1024};
    arr.t[9]  = {d_in[6],  bv_n, 1024};
    arr.t[10] = {d_in[8],  bo_n, 1024};
    arr.t[11] = {d_in[10], b1_n, 4096};
    arr.t[12] = {d_in[12], b2_n, 1024};
    arr.t[13] = {d_in[13], g1_n, 1024};
    arr.t[14] = {d_in[14], be1_n, 1024};
    arr.t[15] = {d_in[15], g2_n, 1024};
    arr.t[16] = {d_in[16], be2_n, 1024};
    normalize_all<<<dim3(2048, 17), blk, 0, stream>>>(arr, flag);

    // QKV projections (M=4096, N=1024, K=1024), B natural [K][N]
    gemm_bn<EPI_PLAIN><<<dim3(16, 64), blk, 0, stream>>>(x_n, 1024, Wq_n, 1024, bq_n, nullptr, Qw, 1024, 1024);
    gemm_bn<EPI_PLAIN><<<dim3(16, 64), blk, 0, stream>>>(x_n, 1024, Wk_n, 1024, bk_n, nullptr, Kw, 1024, 1024);
    gemm_bn<EPI_VT>   <<<dim3(16, 64), blk, 0, stream>>>(x_n, 1024, Wv_n, 1024, bv_n, nullptr, Vt, 1024, 1024);

    // attention (grid: 128 q-tiles x 32 (b,h))
    attn_kernel<<<dim3(128, 32), blk, 0, stream>>>(Qw, Kw, Vt, ctx);

    // out-proj + residual, LN1 (ws-internal stores stay bf16: flag=nullptr)
    gemm_bn<EPI_RES><<<dim3(16, 64), blk, 0, stream>>>(ctx, 1024, Wo_n, 1024, bo_n, x_n, ln1, 1024, 1024);
    ln_kernel<<<4096, blk, 0, stream>>>(ln1, g1_n, be1_n, x1, nullptr);

    // FF: gelu(x1@W1+b1)@W2+b2 + x1, LN2 -> d_out (dtype per flag)
    gemm_bn<EPI_GELU><<<dim3(64, 64), blk, 0, stream>>>(x1, 1024, W1_n, 4096, b1_n, nullptr, ff1, 4096, 1024);
    gemm_bn<EPI_RES> <<<dim3(16, 64), blk, 0, stream>>>(ff1, 4096, W2_n, 1024, b2_n, x1, ff2, 1024, 4096);
    ln_kernel<<<4096, blk, 0, stream>>>(ff2, g2_n, be2_n, d_out, flag);
}

// Round 4
// 531.630 us; speedup vs baseline: 1.3395x; 1.3395x over previous
//
#include <hip/hip_runtime.h>
#include <hip/hip_bf16.h>
#include <math.h>

typedef __bf16 bhalf;
typedef __bf16 bhalf8 __attribute__((ext_vector_type(8)));
typedef float  floatx4 __attribute__((ext_vector_type(4)));
typedef float  floatx8 __attribute__((ext_vector_type(8)));
typedef unsigned short ushort_t;
typedef unsigned short ushort8 __attribute__((ext_vector_type(8)));

#define MFMA16(a, b, c) __builtin_amdgcn_mfma_f32_16x16x32_bf16((a), (b), (c), 0, 0, 0)

enum { EPI_PLAIN = 0, EPI_RES = 1, EPI_GELU = 2, EPI_VT = 3 };

// ---------------------------------------------------------------------------
// Dtype detector (inputs are fp32 per reference; keep robustness): flag=1 fp32.
// ---------------------------------------------------------------------------
__global__ __launch_bounds__(256) void detect_dtype(const ushort_t* __restrict__ x,
                                                    int* __restrict__ flag)
{
    __shared__ int tot;
    if (threadIdx.x == 0) tot = 0;
    __syncthreads();
    int cnt = 0;
    for (int i = threadIdx.x; i < 8192; i += 256) {
        const ushort_t u = x[2 * i];
        const int e = (u >> 7) & 0xFF;
        if (e >= 0x90) ++cnt;
    }
    atomicAdd(&tot, cnt);
    __syncthreads();
    if (threadIdx.x == 0) flag[0] = (tot > 64) ? 1 : 0;
}

// ---------------------------------------------------------------------------
// Normalize all inputs to bf16 ws copies (fp32 -> cvt, bf16 -> copy).
// ---------------------------------------------------------------------------
struct Cvt { const void* s; bhalf* d; int n; };
struct CvtArr { Cvt t[17]; };

__global__ __launch_bounds__(256) void normalize_all(CvtArr a, const int* __restrict__ flag)
{
    const Cvt c = a.t[blockIdx.y];
    const int i = (blockIdx.x * 256 + threadIdx.x) * 8;
    if (i >= c.n) return;
    if (*flag) {
        const floatx8 v = *(const floatx8*)((const float*)c.s + i);
        bhalf8 o;
#pragma unroll
        for (int j = 0; j < 8; ++j) o[j] = (bhalf)v[j];
        *(bhalf8*)(c.d + i) = o;
    } else {
        *(ushort8*)((ushort_t*)c.d + i) = *(const ushort8*)((const ushort_t*)c.s + i);
    }
}

// ---------------------------------------------------------------------------
// GEMM: C[M,N] = A[M,K] @ B[K,N] + bias, B natural [K][N] (bf16), 64x64 tile.
// (unchanged from round 3 — verified correct)
// ---------------------------------------------------------------------------
template <int EPI>
__global__ __launch_bounds__(256) void gemm_bn(
    const bhalf* __restrict__ A, int lda,
    const bhalf* __restrict__ B, int ldb,
    const bhalf* __restrict__ bias,
    const bhalf* __restrict__ resid,
    bhalf* __restrict__ C, int ldc, int K)
{
    __shared__ __align__(16) bhalf As[64 * 72];
    __shared__ __align__(16) bhalf Bs[64 * 72];

    const int tid  = threadIdx.x;
    const int lane = tid & 63;
    const int w    = tid >> 6;
    const int l15  = lane & 15;
    const int q    = lane >> 4;
    const int wm   = (w >> 1) * 32;
    const int wn   = (w & 1) * 32;
    const int n0   = blockIdx.x * 64;
    const int m0   = blockIdx.y * 64;

    const int tr = tid >> 3;
    const int tc = (tid & 7) * 8;
    const int u  = tid & 7;

    floatx4 acc[2][2];
#pragma unroll
    for (int i = 0; i < 2; ++i)
#pragma unroll
        for (int j = 0; j < 2; ++j) acc[i][j] = (floatx4){0.f, 0.f, 0.f, 0.f};

    const int c0 = tr >> 3;
    const int c1 = (tr + 32) >> 3;

    for (int k0 = 0; k0 < K; k0 += 64) {
        const bhalf* ga = A + (size_t)(m0 + tr) * lda + k0 + tc;
        const bhalf* gb = B + (size_t)(k0 + tr) * ldb + n0 + tc;
        bhalf8 a0 = *(const bhalf8*)ga;
        bhalf8 a1 = *(const bhalf8*)(ga + (size_t)32 * lda);
        bhalf8 b0 = *(const bhalf8*)gb;
        bhalf8 b1 = *(const bhalf8*)(gb + (size_t)32 * ldb);
        __syncthreads();
        *(bhalf8*)&As[tr * 72 + tc]        = a0;
        *(bhalf8*)&As[(tr + 32) * 72 + tc] = a1;
#pragma unroll
        for (int j = 0; j < 8; ++j) {
            Bs[(tc + j) * 72 + ((c0 ^ u) << 3) + (tr & 7)] = b0[j];
            Bs[(tc + j) * 72 + ((c1 ^ u) << 3) + (tr & 7)] = b1[j];
        }
        __syncthreads();
#pragma unroll
        for (int s = 0; s < 2; ++s) {
            bhalf8 af0 = *(const bhalf8*)&As[(wm + l15) * 72 + s * 32 + q * 8];
            bhalf8 af1 = *(const bhalf8*)&As[(wm + 16 + l15) * 72 + s * 32 + q * 8];
            const int nb0 = wn + l15;
            const int nb1 = wn + 16 + l15;
            bhalf8 bf0 = *(const bhalf8*)&Bs[nb0 * 72 + (((s * 4 + q) ^ ((nb0 >> 3) & 7)) << 3)];
            bhalf8 bf1 = *(const bhalf8*)&Bs[nb1 * 72 + (((s * 4 + q) ^ ((nb1 >> 3) & 7)) << 3)];
            acc[0][0] = MFMA16(af0, bf0, acc[0][0]);
            acc[0][1] = MFMA16(af0, bf1, acc[0][1]);
            acc[1][0] = MFMA16(af1, bf0, acc[1][0]);
            acc[1][1] = MFMA16(af1, bf1, acc[1][1]);
        }
    }

#pragma unroll
    for (int mt = 0; mt < 2; ++mt)
#pragma unroll
        for (int nt = 0; nt < 2; ++nt) {
            const int col = n0 + wn + nt * 16 + l15;
            const float bv = (float)bias[col];
#pragma unroll
            for (int r = 0; r < 4; ++r) {
                const int row = m0 + wm + mt * 16 + q * 4 + r;
                float v = acc[mt][nt][r] + bv;
                if constexpr (EPI == EPI_PLAIN) {
                    C[(size_t)row * ldc + col] = (bhalf)v;
                } else if constexpr (EPI == EPI_RES) {
                    v += (float)resid[(size_t)row * ldc + col];
                    C[(size_t)row * ldc + col] = (bhalf)v;
                } else if constexpr (EPI == EPI_GELU) {
                    v = 0.5f * v * (1.f + erff(v * 0.70710678118654752f));
                    C[(size_t)row * ldc + col] = (bhalf)v;
                } else {  // EPI_VT
                    const int b = row >> 11, l = row & 2047;
                    const int h = col >> 6, kk = col & 63;
                    C[(((size_t)(b * 16 + h) * 64 + kk) << 11) + l] = (bhalf)v;
                }
            }
        }
}

// ---------------------------------------------------------------------------
// Flash attention: block = (b,h) x 64-query tile, 4 waves x 16 q-rows.
// Iterates 32 K-tiles (64 keys): Ks[key][dim], Vs[dk][key] staged in LDS
// (coalesced 128B rows); S via MFMA with Q in registers; online softmax in
// registers (stats per (q,r), shuffle-reduce over 16-lane group); P written
// to a wave-private LDS tile and re-read as A-frags for PV (no barrier:
// wave wq only touches Ps rows wq*16..wq*16+15).
// LDS = 3 x 9216B = 27.6 KB -> 5 blocks/CU.
// ---------------------------------------------------------------------------
__global__ __launch_bounds__(256) void flash_attn(
    const bhalf* __restrict__ Q, const bhalf* __restrict__ Km,
    const bhalf* __restrict__ Vt, bhalf* __restrict__ ctx)
{
    __shared__ __align__(16) bhalf Ks[64][72];
    __shared__ __align__(16) bhalf Vs[64][72];
    __shared__ __align__(16) bhalf Ps[64][72];

    const int tid  = threadIdx.x;
    const int lane = tid & 63;
    const int wq   = tid >> 6;
    const int l15  = lane & 15;
    const int q    = lane >> 4;
    const int bh   = blockIdx.y;
    const int b    = bh >> 4, h = bh & 15;
    const int l0   = blockIdx.x * 64;

    // Q A-frags: rows l0 + wq*16 + l15 (A: m=lane&15, k=quad*8+j; m89-verified)
    const bhalf* qp = Q + ((size_t)(b * 2048 + l0 + wq * 16 + l15)) * 1024 + h * 64 + q * 8;
    const bhalf8 aQ0 = *(const bhalf8*)qp;
    const bhalf8 aQ1 = *(const bhalf8*)(qp + 32);

    float m_run[4], l_run[4];
    floatx4 o[4];
#pragma unroll
    for (int r = 0; r < 4; ++r) { m_run[r] = -3.0e38f; l_run[r] = 0.f; }
#pragma unroll
    for (int ot = 0; ot < 4; ++ot) o[ot] = (floatx4){0.f, 0.f, 0.f, 0.f};

    const int srow = tid >> 2;         // 0..63
    const int sc4  = (tid & 3) * 8;    // 0,8,16,24
    const bhalf* kbase = Km + ((size_t)(b * 2048)) * 1024 + h * 64;
    const bhalf* vbase = Vt + ((size_t)(bh * 64 + srow)) * 2048;

    for (int kt = 0; kt < 2048; kt += 64) {
        __syncthreads();  // previous tile's Ks/Vs reads complete
        const bhalf* kg = kbase + (size_t)(kt + srow) * 1024 + sc4;
        *(bhalf8*)&Ks[srow][sc4]      = *(const bhalf8*)kg;
        *(bhalf8*)&Ks[srow][sc4 + 32] = *(const bhalf8*)(kg + 32);
        const bhalf* vg = vbase + kt + sc4;
        *(bhalf8*)&Vs[srow][sc4]      = *(const bhalf8*)vg;
        *(bhalf8*)&Vs[srow][sc4 + 32] = *(const bhalf8*)(vg + 32);
        __syncthreads();

        // ---- S = (Q K^T) * 0.125 : 8 MFMA ----
        floatx4 s[4];
#pragma unroll
        for (int nt = 0; nt < 4; ++nt) {
            s[nt] = (floatx4){0.f, 0.f, 0.f, 0.f};
            bhalf8 bK0 = *(const bhalf8*)&Ks[nt * 16 + l15][q * 8];
            bhalf8 bK1 = *(const bhalf8*)&Ks[nt * 16 + l15][32 + q * 8];
            s[nt] = MFMA16(aQ0, bK0, s[nt]);
            s[nt] = MFMA16(aQ1, bK1, s[nt]);
        }
#pragma unroll
        for (int nt = 0; nt < 4; ++nt)
#pragma unroll
            for (int r = 0; r < 4; ++r) s[nt][r] *= 0.125f;

        // ---- online softmax: row stats per (q,r), reduce over 16-lane group ----
        float mt[4];
#pragma unroll
        for (int r = 0; r < 4; ++r) {
            mt[r] = fmaxf(fmaxf(s[0][r], s[1][r]), fmaxf(s[2][r], s[3][r]));
#pragma unroll
            for (int off = 1; off < 16; off <<= 1)
                mt[r] = fmaxf(mt[r], __shfl_xor(mt[r], off));
        }
        float alpha[4];
#pragma unroll
        for (int r = 0; r < 4; ++r) {
            const float mn = fmaxf(m_run[r], mt[r]);
            alpha[r] = __expf(m_run[r] - mn);
            m_run[r] = mn;
        }
        float rs[4] = {0.f, 0.f, 0.f, 0.f};
#pragma unroll
        for (int nt = 0; nt < 4; ++nt)
#pragma unroll
            for (int r = 0; r < 4; ++r) {
                const float pv = __expf(s[nt][r] - m_run[r]);
                rs[r] += pv;
                Ps[wq * 16 + q * 4 + r][nt * 16 + l15] = (bhalf)pv;
            }
#pragma unroll
        for (int r = 0; r < 4; ++r) {
#pragma unroll
            for (int off = 1; off < 16; off <<= 1) rs[r] += __shfl_xor(rs[r], off);
            l_run[r] = l_run[r] * alpha[r] + rs[r];
        }
#pragma unroll
        for (int ot = 0; ot < 4; ++ot)
#pragma unroll
            for (int r = 0; r < 4; ++r) o[ot][r] *= alpha[r];

        // ---- O += P V : 8 MFMA (Ps rows wave-private; lgkmcnt orders wr->rd) ----
#pragma unroll
        for (int kc = 0; kc < 2; ++kc) {
            bhalf8 aP = *(const bhalf8*)&Ps[wq * 16 + l15][kc * 32 + q * 8];
#pragma unroll
            for (int ot = 0; ot < 4; ++ot) {
                bhalf8 bV = *(const bhalf8*)&Vs[ot * 16 + l15][kc * 32 + q * 8];
                o[ot] = MFMA16(aP, bV, o[ot]);
            }
        }
    }

    // ---- epilogue: normalize, faithful reshape (b,h,L,dk)->(b,L,d) ----
    float inv[4];
#pragma unroll
    for (int r = 0; r < 4; ++r) inv[r] = 1.f / l_run[r];
#pragma unroll
    for (int ot = 0; ot < 4; ++ot)
#pragma unroll
        for (int r = 0; r < 4; ++r) {
            const int l = l0 + wq * 16 + q * 4 + r;
            const int kk = ot * 16 + l15;
            const int R = h * 128 + (l >> 4);
            const int Cc = (l & 15) * 64 + kk;
            ctx[((size_t)(b * 2048 + R)) * 1024 + Cc] = (bhalf)(o[ot][r] * inv[r]);
        }
}

// ---------------------------------------------------------------------------
// Row LayerNorm over 1024 cols, one block per row, fp32 stats.
// ---------------------------------------------------------------------------
__global__ __launch_bounds__(256) void ln_kernel(
    const bhalf* __restrict__ X, const bhalf* __restrict__ g,
    const bhalf* __restrict__ be, void* __restrict__ out, const int* __restrict__ flag)
{
    __shared__ float red[8];
    __shared__ float stats[2];
    const int row = blockIdx.x;
    const int tid = threadIdx.x;
    const bhalf* xr = X + (size_t)row * 1024;
    float v[4], s1 = 0.f, s2 = 0.f;
#pragma unroll
    for (int i = 0; i < 4; ++i) {
        v[i] = (float)xr[tid * 4 + i];
        s1 += v[i];
        s2 += v[i] * v[i];
    }
#pragma unroll
    for (int off = 32; off >= 1; off >>= 1) {
        s1 += __shfl_down(s1, off, 64);
        s2 += __shfl_down(s2, off, 64);
    }
    if ((tid & 63) == 0) { red[tid >> 6] = s1; red[4 + (tid >> 6)] = s2; }
    __syncthreads();
    if (tid == 0) {
        const float t1 = red[0] + red[1] + red[2] + red[3];
        const float t2 = red[4] + red[5] + red[6] + red[7];
        const float mu = t1 * (1.f / 1024.f);
        const float var = t2 * (1.f / 1024.f) - mu * mu;
        stats[0] = mu;
        stats[1] = rsqrtf(var + 1e-5f);
    }
    __syncthreads();
    const float mu = stats[0], rs = stats[1];
    const bool f32 = flag && (*flag != 0);
#pragma unroll
    for (int i = 0; i < 4; ++i) {
        const int j = tid * 4 + i;
        const float o = ((v[i] - mu) * rs) * (float)g[j] + (float)be[j];
        if (f32) ((float*)out)[(size_t)row * 1024 + j] = o;
        else     ((bhalf*)out)[(size_t)row * 1024 + j] = (bhalf)o;
    }
}

// ---------------------------------------------------------------------------
extern "C" void kernel_launch(void* const* d_in, const int* in_sizes, int n_in,
                              void* d_out, int out_size, void* d_ws, size_t ws_size,
                              hipStream_t stream)
{
    (void)in_sizes; (void)n_in; (void)out_size; (void)ws_size;

    char* p = (char*)d_ws;
    const size_t MB = 1024 * 1024;
    int*   flag = (int*)p;
    bhalf* vecs = (bhalf*)(p + 128 * 1024);
    bhalf* Qw   = (bhalf*)(p + 1 * MB);
    bhalf* Kw   = (bhalf*)(p + 9 * MB);
    bhalf* Vt   = (bhalf*)(p + 17 * MB);
    bhalf* ctx  = (bhalf*)(p + 25 * MB);
    bhalf* x_n  = (bhalf*)(p + 33 * MB);
    bhalf* Wq_n = (bhalf*)(p + 41 * MB);
    bhalf* Wk_n = (bhalf*)(p + 43 * MB);
    bhalf* Wv_n = (bhalf*)(p + 45 * MB);
    bhalf* Wo_n = (bhalf*)(p + 47 * MB);
    bhalf* W1_n = (bhalf*)(p + 49 * MB);
    bhalf* W2_n = (bhalf*)(p + 57 * MB);
    bhalf* ff1  = (bhalf*)(p + 17 * MB);  // 32 MB, aliases Vt+ctx+x_n (dead)
    bhalf* ln1  = Qw;
    bhalf* x1   = Kw;
    bhalf* ff2  = Qw;

    bhalf* bq_n = vecs + 0 * 4096, *bk_n = vecs + 1 * 4096, *bv_n = vecs + 2 * 4096;
    bhalf* bo_n = vecs + 3 * 4096, *b1_n = vecs + 4 * 4096, *b2_n = vecs + 5 * 4096;
    bhalf* g1_n = vecs + 6 * 4096, *be1_n = vecs + 7 * 4096;
    bhalf* g2_n = vecs + 8 * 4096, *be2_n = vecs + 9 * 4096;

    const dim3 blk(256);

    detect_dtype<<<1, blk, 0, stream>>>((const ushort_t*)d_in[0], flag);

    CvtArr arr;
    arr.t[0]  = {d_in[0],  x_n,  2 * 2048 * 1024};
    arr.t[1]  = {d_in[1],  Wq_n, 1024 * 1024};
    arr.t[2]  = {d_in[3],  Wk_n, 1024 * 1024};
    arr.t[3]  = {d_in[5],  Wv_n, 1024 * 1024};
    arr.t[4]  = {d_in[7],  Wo_n, 1024 * 1024};
    arr.t[5]  = {d_in[9],  W1_n, 1024 * 4096};
    arr.t[6]  = {d_in[11], W2_n, 4096 * 1024};
    arr.t[7]  = {d_in[2],  bq_n, 1024};
    arr.t[8]  = {d_in[4],  bk_n, 1024};
    arr.t[9]  = {d_in[6],  bv_n, 1024};
    arr.t[10] = {d_in[8],  bo_n, 1024};
    arr.t[11] = {d_in[10], b1_n, 4096};
    arr.t[12] = {d_in[12], b2_n, 1024};
    arr.t[13] = {d_in[13], g1_n, 1024};
    arr.t[14] = {d_in[14], be1_n, 1024};
    arr.t[15] = {d_in[15], g2_n, 1024};
    arr.t[16] = {d_in[16], be2_n, 1024};
    normalize_all<<<dim3(2048, 17), blk, 0, stream>>>(arr, flag);

    // QKV projections (M=4096, N=1024, K=1024)
    gemm_bn<EPI_PLAIN><<<dim3(16, 64), blk, 0, stream>>>(x_n, 1024, Wq_n, 1024, bq_n, nullptr, Qw, 1024, 1024);
    gemm_bn<EPI_PLAIN><<<dim3(16, 64), blk, 0, stream>>>(x_n, 1024, Wk_n, 1024, bk_n, nullptr, Kw, 1024, 1024);
    gemm_bn<EPI_VT>   <<<dim3(16, 64), blk, 0, stream>>>(x_n, 1024, Wv_n, 1024, bv_n, nullptr, Vt, 1024, 1024);

    // flash attention: 32 q-tiles x 32 (b,h)
    flash_attn<<<dim3(32, 32), blk, 0, stream>>>(Qw, Kw, Vt, ctx);

    // out-proj + residual, LN1
    gemm_bn<EPI_RES><<<dim3(16, 64), blk, 0, stream>>>(ctx, 1024, Wo_n, 1024, bo_n, x_n, ln1, 1024, 1024);
    ln_kernel<<<4096, blk, 0, stream>>>(ln1, g1_n, be1_n, x1, nullptr);

    // FF: gelu(x1@W1+b1)@W2+b2 + x1, LN2 -> d_out
    gemm_bn<EPI_GELU><<<dim3(64, 64), blk, 0, stream>>>(x1, 1024, W1_n, 4096, b1_n, nullptr, ff1, 4096, 1024);
    gemm_bn<EPI_RES> <<<dim3(16, 64), blk, 0, stream>>>(ff1, 4096, W2_n, 1024, b2_n, x1, ff2, 1024, 4096);
    ln_kernel<<<4096, blk, 0, stream>>>(ff2, g2_n, be2_n, d_out, flag);
}